// Round 13
// baseline (172.867 us; speedup 1.0000x reference)
//
#include <hip/hip_runtime.h>
#include <math.h>

#define N 4096
#define DIN 512
#define D 32
#define JC 8

typedef float v2f __attribute__((ext_vector_type(2)));
__device__ __forceinline__ v2f fma2(v2f a, float b, v2f c) {
  v2f bb; bb.x = b; bb.y = b;
  return __builtin_elementwise_fma(a, bb, c);
}

// ---------------- encoder: x[4096,512] -> latent[4096,32] + normed rows, fused ----------------
// R6: k-split layer 1 (w1 read once per block; partials reduced via LDS). Left top-5.
__global__ __launch_bounds__(256) void enc_kernel(
    const float* __restrict__ x,
    const float* __restrict__ w1, const float* __restrict__ b1,
    const float* __restrict__ w2, const float* __restrict__ b2,
    const float* __restrict__ w3, const float* __restrict__ b3,
    float* __restrict__ latent, float* __restrict__ normed) {
  __shared__ float xs[8][512];       // 16 KB
  __shared__ float h1p[4][8][128];   // 16 KB layer-1 partials (per k-quarter)
  __shared__ float h1s[8][128];      // 4 KB
  __shared__ float h2s[8][64];       // 2 KB
  __shared__ float w2s[128][64];     // 32 KB
  __shared__ float w3s[64][32];      // 8 KB   -> total 78 KB = 2 blocks/CU
  const int t = threadIdx.x;
  const int r0 = blockIdx.x * 8;

  // stage x rows + w2 + w3 into LDS (one barrier covers all)
  const float4* xg = (const float4*)(x + (size_t)r0 * DIN);
  float4* xl = (float4*)&xs[0][0];
#pragma unroll
  for (int i = 0; i < 4; ++i) xl[t + i * 256] = xg[t + i * 256];
  float4* w2l = (float4*)&w2s[0][0];
  const float4* w2g = (const float4*)w2;
#pragma unroll
  for (int i = 0; i < 8; ++i) w2l[t + i * 256] = w2g[t + i * 256];
  float4* w3l = (float4*)&w3s[0][0];
  const float4* w3g = (const float4*)w3;
#pragma unroll
  for (int i = 0; i < 2; ++i) w3l[t + i * 256] = w3g[t + i * 256];
  __syncthreads();

  // layer 1: 512 -> 128. wave kq handles its k-quarter for all 8 rows x 2 cols.
  {
    const int jc2 = (t & 63) * 2;
    const int kq = t >> 6;
    const int kb = kq * 128;
    float a0[8], a1[8];
#pragma unroll
    for (int r = 0; r < 8; ++r) { a0[r] = 0.f; a1[r] = 0.f; }
    const float* wp = w1 + (size_t)kb * 128 + jc2;

#define ENC_LD4(P0, P1, P2, P3, KK)                          \
    P0 = *(const float2*)&wp[(size_t)(KK) * 128];            \
    P1 = *(const float2*)&wp[(size_t)((KK) + 1) * 128];      \
    P2 = *(const float2*)&wp[(size_t)((KK) + 2) * 128];      \
    P3 = *(const float2*)&wp[(size_t)((KK) + 3) * 128];

#define ENC_STEP(W0, WA, WB, WC, KK)                                   \
    {                                                                  \
      _Pragma("unroll")                                                \
      for (int r = 0; r < 8; ++r) {                                    \
        const float4 xv = *(const float4*)&xs[r][kb + (KK)];           \
        a0[r] = fmaf(xv.x, W0.x, a0[r]); a1[r] = fmaf(xv.x, W0.y, a1[r]); \
        a0[r] = fmaf(xv.y, WA.x, a0[r]); a1[r] = fmaf(xv.y, WA.y, a1[r]); \
        a0[r] = fmaf(xv.z, WB.x, a0[r]); a1[r] = fmaf(xv.z, WB.y, a1[r]); \
        a0[r] = fmaf(xv.w, WC.x, a0[r]); a1[r] = fmaf(xv.w, WC.y, a1[r]); \
      }                                                                \
    }

    float2 A0, A1, A2, A3, B0, B1, B2, B3, C0, C1, C2, C3, D0, D1, D2, D3;
    ENC_LD4(A0, A1, A2, A3, 0)
    ENC_LD4(B0, B1, B2, B3, 4)
    ENC_LD4(C0, C1, C2, C3, 8)
    ENC_LD4(D0, D1, D2, D3, 12)
    for (int kk = 0; kk < 128; kk += 16) {
      ENC_STEP(A0, A1, A2, A3, kk + 0);
      if (kk + 16 < 128) { ENC_LD4(A0, A1, A2, A3, kk + 16) }
      ENC_STEP(B0, B1, B2, B3, kk + 4);
      if (kk + 20 < 128) { ENC_LD4(B0, B1, B2, B3, kk + 20) }
      ENC_STEP(C0, C1, C2, C3, kk + 8);
      if (kk + 24 < 128) { ENC_LD4(C0, C1, C2, C3, kk + 24) }
      ENC_STEP(D0, D1, D2, D3, kk + 12);
      if (kk + 28 < 128) { ENC_LD4(D0, D1, D2, D3, kk + 28) }
    }
#undef ENC_STEP
#undef ENC_LD4
#pragma unroll
    for (int r = 0; r < 8; ++r) {
      h1p[kq][r][jc2] = a0[r];
      h1p[kq][r][jc2 + 1] = a1[r];
    }
  }
  __syncthreads();

  // reduce the 4 k-quarter partials + bias + relu (1024 outputs)
#pragma unroll
  for (int e0 = 0; e0 < 1024; e0 += 256) {
    const int e = e0 + t;
    const int r = e >> 7, c = e & 127;
    const float s = b1[c] + ((h1p[0][r][c] + h1p[1][r][c]) + (h1p[2][r][c] + h1p[3][r][c]));
    h1s[r][c] = fmaxf(s, 0.f);
  }
  __syncthreads();

  // layer 2: 128 -> 64, relu. weights from LDS (w2s), h1 broadcast reads
  {
    const int j = t & 63, rg = t >> 6;
    const int ra = rg * 2, rb = ra + 1;
    float a0 = b2[j], a1 = b2[j];
#pragma unroll 8
    for (int kk = 0; kk < 128; ++kk) {
      const float w = w2s[kk][j];
      a0 = fmaf(h1s[ra][kk], w, a0);
      a1 = fmaf(h1s[rb][kk], w, a1);
    }
    h2s[ra][j] = fmaxf(a0, 0.f);
    h2s[rb][j] = fmaxf(a1, 0.f);
  }
  __syncthreads();

  // layer 3: 64 -> 32 + fused row-normalize (shfl reduce over the 32 j-lanes)
  {
    const int j = t & 31, og = t >> 5;  // 8 rows, 1 per group
    float acc = b3[j];
#pragma unroll 8
    for (int kk = 0; kk < 64; ++kk) acc = fmaf(h2s[og][kk], w3s[kk][j], acc);
    float s2 = acc * acc;
    s2 += __shfl_xor(s2, 1);
    s2 += __shfl_xor(s2, 2);
    s2 += __shfl_xor(s2, 4);
    s2 += __shfl_xor(s2, 8);
    s2 += __shfl_xor(s2, 16);
    const float inv = 1.0f / (sqrtf(s2) + 1e-12f);
    const size_t off = (size_t)(r0 + og) * D + j;
    latent[off] = acc;
    normed[off] = acc * inv;
  }
}

// ---------------- graph pool partials: block (bi, bj) covers 64 i-rows x 512 j ----------------
// R11: 2 i-rows/thread + packed fma + XOR swizzle (conflict-free) + butterfly reduce.
__global__ __launch_bounds__(256) __attribute__((amdgpu_waves_per_eu(2, 2)))
void pool_kernel(const float* __restrict__ normed,
                 const float* __restrict__ latent,
                 float* __restrict__ pacc,
                 float* __restrict__ pdeg) {
  __shared__ float smem[8192];
  float* nt = smem;
  float* lt = smem + 4096;
  const int t = threadIdx.x;
  const int jg = t & 7, ip = t >> 3;  // ip in [0,32)
  const int i0 = blockIdx.x * 64;
  const int j0 = blockIdx.y * 512;

  v2f nip[32];
  {
    const float* nr0 = normed + (size_t)(i0 + ip) * D;
    const float* nr1 = normed + (size_t)(i0 + ip + 32) * D;
#pragma unroll
    for (int c = 0; c < 32; ++c) { nip[c].x = nr0[c]; nip[c].y = nr1[c]; }
  }

  v2f accp[32], deg2;
#pragma unroll
  for (int c = 0; c < 32; ++c) { accp[c].x = 0.f; accp[c].y = 0.f; }
  deg2.x = 0.f; deg2.y = 0.f;

  for (int jt = j0; jt < j0 + 512; jt += 128) {
    __syncthreads();
    const float4* ng = (const float4*)(normed + (size_t)jt * D);
    const float4* lg = (const float4*)(latent + (size_t)jt * D);
    float4* ntl = (float4*)nt;
    float4* ltl = (float4*)lt;
#pragma unroll
    for (int i = 0; i < 4; ++i) {
      const int gidx = t + i * 256;  // [0,1024): row r = gidx>>3, slot cc = gidx&7
      const int r = gidx >> 3, cc = gidx & 7, slot = cc ^ (r & 7);
      ntl[r * 8 + slot] = ng[gidx];
      ltl[r * 8 + slot] = lg[gidx];
    }
    __syncthreads();
#pragma unroll 2
    for (int jj = jg; jj < 128; jj += 8) {
      const float4* nr = (const float4*)nt + jj * 8;
      const int sw = jj & 7;
      v2f s2; s2.x = 0.f; s2.y = 0.f;
#pragma unroll
      for (int c4 = 0; c4 < 8; ++c4) {
        const float4 nv = nr[c4 ^ sw];
        s2 = fma2(nip[c4 * 4 + 0], nv.x, s2);
        s2 = fma2(nip[c4 * 4 + 1], nv.y, s2);
        s2 = fma2(nip[c4 * 4 + 2], nv.z, s2);
        s2 = fma2(nip[c4 * 4 + 3], nv.w, s2);
      }
      if (s2.x >= 0.9f || s2.y >= 0.9f) {
        v2f m2;
        m2.x = (s2.x >= 0.9f) ? 1.f : 0.f;
        m2.y = (s2.y >= 0.9f) ? 1.f : 0.f;
        deg2 += m2;
        const float4* lr = (const float4*)lt + jj * 8;
#pragma unroll
        for (int c4 = 0; c4 < 8; ++c4) {
          const float4 lv = lr[c4 ^ sw];
          accp[c4 * 4 + 0] = fma2(m2, lv.x, accp[c4 * 4 + 0]);
          accp[c4 * 4 + 1] = fma2(m2, lv.y, accp[c4 * 4 + 1]);
          accp[c4 * 4 + 2] = fma2(m2, lv.z, accp[c4 * 4 + 2]);
          accp[c4 * 4 + 3] = fma2(m2, lv.w, accp[c4 * 4 + 3]);
        }
      }
    }
  }
  // butterfly-reduce the 8 jg partials (jg = lane bits 0..2)
#pragma unroll
  for (int m = 1; m <= 4; m <<= 1) {
#pragma unroll
    for (int c = 0; c < 32; ++c) {
      accp[c].x += __shfl_xor(accp[c].x, m);
      accp[c].y += __shfl_xor(accp[c].y, m);
    }
    deg2.x += __shfl_xor(deg2.x, m);
    deg2.y += __shfl_xor(deg2.y, m);
  }
  if (jg == 0) {
    float* pa0 = pacc + ((size_t)blockIdx.y * N + i0 + ip) * 32;
    float* pa1 = pacc + ((size_t)blockIdx.y * N + i0 + ip + 32) * 32;
#pragma unroll
    for (int c = 0; c < 32; ++c) {
      pa0[c] = accp[c].x;
      pa1[c] = accp[c].y;
    }
    pdeg[(size_t)blockIdx.y * N + i0 + ip] = deg2.x;
    pdeg[(size_t)blockIdx.y * N + i0 + ip + 32] = deg2.y;
  }
}

// ---------------- fused QKV projection (+ optional pool-combine producing h) ----------------
// R12: pool_combine folded in (blk 0). Bit-identical combine (jc ascending, one division).
__global__ __launch_bounds__(256) void qkv_kernel(
    float* __restrict__ h,
    const float* __restrict__ wq, const float* __restrict__ bq,
    const float* __restrict__ wk, const float* __restrict__ bk,
    const float* __restrict__ wv, const float* __restrict__ bv,
    float* __restrict__ q, float* __restrict__ k, float* __restrict__ v,
    int* __restrict__ kmax2i,
    const float* __restrict__ latent,
    const float* __restrict__ pacc,
    const float* __restrict__ pdeg,
    int fuse_combine) {
  __shared__ float hs[32][32];
  __shared__ float wsm[3][32][32];
  __shared__ int kred[4];
  const int t = threadIdx.x;
  const int r0 = blockIdx.x * 32;
  if (t < 4) kred[t] = 0;
  if (fuse_combine) {
    const int el = t * 4;                 // element offset within the 32x32 tile
    const int gi = r0 + (el >> 5);        // global row (all 4 elems same row)
    float4 s4 = make_float4(0.f, 0.f, 0.f, 0.f);
    float dg = 0.f;
#pragma unroll
    for (int jc = 0; jc < JC; ++jc) {
      const float4 p4 = *(const float4*)&pacc[(size_t)jc * N * 32 + (size_t)r0 * 32 + el];
      s4.x += p4.x; s4.y += p4.y; s4.z += p4.z; s4.w += p4.w;
      dg += pdeg[(size_t)jc * N + gi];
    }
    const float4 l4 = *(const float4*)&latent[(size_t)r0 * 32 + el];
    float4 h4;
    h4.x = l4.x + s4.x / dg;
    h4.y = l4.y + s4.y / dg;
    h4.z = l4.z + s4.z / dg;
    h4.w = l4.w + s4.w / dg;
    ((float4*)&hs[0][0])[t] = h4;
    *(float4*)&h[(size_t)r0 * 32 + el] = h4;
  } else {
    ((float4*)&hs[0][0])[t] = ((const float4*)(h + (size_t)r0 * 32))[t];
  }
  ((float4*)&wsm[0][0][0])[t] = ((const float4*)wq)[t];
  ((float4*)&wsm[1][0][0])[t] = ((const float4*)wk)[t];
  ((float4*)&wsm[2][0][0])[t] = ((const float4*)wv)[t];
  __syncthreads();
  const int j = t & 31, og = t >> 5;
  const int head = j >> 3;
  float aq[4], ak[4], av[4];
#pragma unroll
  for (int u = 0; u < 4; ++u) { aq[u] = bq[j]; ak[u] = bk[j]; av[u] = bv[j]; }
  for (int kk = 0; kk < 32; ++kk) {
    const float wqv = wsm[0][kk][j], wkv = wsm[1][kk][j], wvv = wsm[2][kk][j];
#pragma unroll
    for (int u = 0; u < 4; ++u) {
      const float hh = hs[og * 4 + u][kk];
      aq[u] = fmaf(hh, wqv, aq[u]);
      ak[u] = fmaf(hh, wkv, ak[u]);
      av[u] = fmaf(hh, wvv, av[u]);
    }
  }
  const float scale = 1.4426950408889634f * 0.35355339059327373f;  // log2(e)/sqrt(8)
#pragma unroll
  for (int u = 0; u < 4; ++u) {
    const size_t off = (size_t)(r0 + og * 4 + u) * 32 + j;
    q[off] = aq[u] * scale;
    k[off] = ak[u];
    v[off] = av[u];
  }
  // per-(row,head) ||k8||^2 via shfl over the 8 lanes of this head; block-max; global atomicMax
#pragma unroll
  for (int u = 0; u < 4; ++u) {
    float s2 = ak[u] * ak[u];
    s2 += __shfl_xor(s2, 1);
    s2 += __shfl_xor(s2, 2);
    s2 += __shfl_xor(s2, 4);
    if ((j & 7) == 0) atomicMax(&kred[head], __float_as_int(s2));
  }
  __syncthreads();
  if (t < 4) atomicMax(&kmax2i[t], kred[t]);
}

// ---------------- attention partials: block (rowBlk, jChunk); 32 rows x jlen j ----------------
// R13: chunk count is now a LAUNCH parameter (jlen = N/nchunk). Key insight: total LDS
// wave-reads = 128*nchunk blocks x (jlen/2 b128 per thread) = const -- LDS traffic is
// INVARIANT in nchunk (unlike rows/block, the R9 axis). So nchunk 8->16 doubles blocks
// (2048 = 8 blocks/CU: 2048 thr, 128 KB LDS, 64 VGPR x 2048 = 131072 regs -- all exactly
// fit) with zero traffic cost -> stall-hiding TLP doubles. k/v global staging also
// invariant (each row-block reads only its own chunk). Guarded by ws_size (partials 2x).
__global__ __launch_bounds__(256, 4)
void attn_kernel(const float* __restrict__ q,
                 const float* __restrict__ k,
                 const float* __restrict__ v,
                 const int* __restrict__ kmax2i,
                 float* __restrict__ apacc,
                 float* __restrict__ apl,
                 int jlen) {
  __shared__ float4 tiles[1024];  // kls[64*8] | vls[64*8], chunk-XOR swizzled
  float4* kls = tiles;
  float4* vls = tiles + 512;
  const int t = threadIdx.x;
  const int jg = t & 7, head = (t >> 3) & 3, rg = t >> 5;
  const int r0 = blockIdx.x * 32;
  const int j0 = blockIdx.y * jlen;

  const float km2 = __int_as_float(kmax2i[head]);

  // q-row pairs: component c of rows (2pr, 2pr+1) in lo/hi of qq[pr][c]
  v2f qq[2][8], acc[2][8], mneg2[2], l2[2];
#pragma unroll
  for (int pr = 0; pr < 2; ++pr) {
    const float* qr0 = q + (size_t)(r0 + rg * 4 + 2 * pr) * 32 + head * 8;
    const float* qr1 = qr0 + 32;
    const float4 qa0 = ((const float4*)qr0)[0], qb0 = ((const float4*)qr0)[1];
    const float4 qa1 = ((const float4*)qr1)[0], qb1 = ((const float4*)qr1)[1];
    qq[pr][0].x = qa0.x; qq[pr][0].y = qa1.x;
    qq[pr][1].x = qa0.y; qq[pr][1].y = qa1.y;
    qq[pr][2].x = qa0.z; qq[pr][2].y = qa1.z;
    qq[pr][3].x = qa0.w; qq[pr][3].y = qa1.w;
    qq[pr][4].x = qb0.x; qq[pr][4].y = qb1.x;
    qq[pr][5].x = qb0.y; qq[pr][5].y = qb1.y;
    qq[pr][6].x = qb0.z; qq[pr][6].y = qb1.z;
    qq[pr][7].x = qb0.w; qq[pr][7].y = qb1.w;
    const float qn0 = qa0.x * qa0.x + qa0.y * qa0.y + qa0.z * qa0.z + qa0.w * qa0.w +
                      qb0.x * qb0.x + qb0.y * qb0.y + qb0.z * qb0.z + qb0.w * qb0.w;
    const float qn1 = qa1.x * qa1.x + qa1.y * qa1.y + qa1.z * qa1.z + qa1.w * qa1.w +
                      qb1.x * qb1.x + qb1.y * qb1.y + qb1.z * qb1.z + qb1.w * qb1.w;
    mneg2[pr].x = -sqrtf(qn0 * km2);
    mneg2[pr].y = -sqrtf(qn1 * km2);
    l2[pr].x = 0.f; l2[pr].y = 0.f;
#pragma unroll
    for (int c = 0; c < 8; ++c) { acc[pr][c].x = 0.f; acc[pr][c].y = 0.f; }
  }

  // prologue: load tile 0 into registers
  float4 kr0, kr1, vr0, vr1;
  {
    const float4* kg = (const float4*)(k + (size_t)j0 * 32);
    const float4* vg = (const float4*)(v + (size_t)j0 * 32);
    kr0 = kg[t]; kr1 = kg[t + 256];
    vr0 = vg[t]; vr1 = vg[t + 256];
  }

  // precomputed swizzle slots for the two staged quarters
  const int rA = t >> 3, slotA = (t & 7) ^ (rA & 7);
  const int g1 = t + 256;
  const int rB = g1 >> 3, slotB = (g1 & 7) ^ (rB & 7);

  const int h2 = head * 2;
  const int s0 = h2 ^ jg, s1 = (h2 + 1) ^ jg;
  for (int jt = j0; jt < j0 + jlen; jt += 64) {
    __syncthreads();
    kls[rA * 8 + slotA] = kr0;
    kls[rB * 8 + slotB] = kr1;
    vls[rA * 8 + slotA] = vr0;
    vls[rB * 8 + slotB] = vr1;
    __syncthreads();
    if (jt + 64 < j0 + jlen) {
      const float4* kg = (const float4*)(k + (size_t)(jt + 64) * 32);
      const float4* vg = (const float4*)(v + (size_t)(jt + 64) * 32);
      kr0 = kg[t]; kr1 = kg[t + 256];
      vr0 = vg[t]; vr1 = vg[t + 256];
    }
#pragma unroll 2
    for (int it = 0; it < 8; ++it) {
      const int jj = it * 8 + jg;
      const float4 ka = kls[jj * 8 + s0];
      const float4 kb = kls[jj * 8 + s1];
      const float4 va = vls[jj * 8 + s0];
      const float4 vb = vls[jj * 8 + s1];
#pragma unroll
      for (int pr = 0; pr < 2; ++pr) {
        v2f s2 = mneg2[pr];
        s2 = fma2(qq[pr][0], ka.x, s2);
        s2 = fma2(qq[pr][1], ka.y, s2);
        s2 = fma2(qq[pr][2], ka.z, s2);
        s2 = fma2(qq[pr][3], ka.w, s2);
        s2 = fma2(qq[pr][4], kb.x, s2);
        s2 = fma2(qq[pr][5], kb.y, s2);
        s2 = fma2(qq[pr][6], kb.z, s2);
        s2 = fma2(qq[pr][7], kb.w, s2);
        v2f p2;
        p2.x = __builtin_amdgcn_exp2f(s2.x);
        p2.y = __builtin_amdgcn_exp2f(s2.y);
        l2[pr] += p2;
        acc[pr][0] = fma2(p2, va.x, acc[pr][0]);
        acc[pr][1] = fma2(p2, va.y, acc[pr][1]);
        acc[pr][2] = fma2(p2, va.z, acc[pr][2]);
        acc[pr][3] = fma2(p2, va.w, acc[pr][3]);
        acc[pr][4] = fma2(p2, vb.x, acc[pr][4]);
        acc[pr][5] = fma2(p2, vb.y, acc[pr][5]);
        acc[pr][6] = fma2(p2, vb.z, acc[pr][6]);
        acc[pr][7] = fma2(p2, vb.w, acc[pr][7]);
      }
    }
  }
  // butterfly-reduce the 8 jg partials (jg = lane bits 0..2); all lanes end with the sum
#pragma unroll
  for (int pr = 0; pr < 2; ++pr) {
#pragma unroll
    for (int m = 1; m <= 4; m <<= 1) {
#pragma unroll
      for (int c = 0; c < 8; ++c) {
        acc[pr][c].x += __shfl_xor(acc[pr][c].x, m);
        acc[pr][c].y += __shfl_xor(acc[pr][c].y, m);
      }
      l2[pr].x += __shfl_xor(l2[pr].x, m);
      l2[pr].y += __shfl_xor(l2[pr].y, m);
    }
  }
  if (jg == 0) {
    const size_t abase = (size_t)blockIdx.y * N * 32;
    const size_t lbase = (size_t)blockIdx.y * N * 4;
#pragma unroll
    for (int pr = 0; pr < 2; ++pr) {
      const int row0 = r0 + rg * 4 + 2 * pr;
      float* ap0 = apacc + abase + (size_t)row0 * 32 + head * 8;
      float* ap1 = ap0 + 32;
#pragma unroll
      for (int c = 0; c < 8; ++c) {
        ap0[c] = acc[pr][c].x;
        ap1[c] = acc[pr][c].y;
      }
      apl[lbase + (size_t)row0 * 4 + head] = l2[pr].x;
      apl[lbase + (size_t)(row0 + 1) * 4 + head] = l2[pr].y;
    }
  }
}

// ---------------- fused: attn-combine + O-proj + residual + LN1 + FFN + residual + LN2 ----
// R12 fusion; R13: chunk count (nchunk) is a runtime parameter matching attn's grid.y.
__global__ __launch_bounds__(256) void oln1ffn_kernel(
    const float* __restrict__ apacc, const float* __restrict__ apl,
    const float* __restrict__ wo, const float* __restrict__ bo,
    const float* __restrict__ ln1g, const float* __restrict__ ln1b,
    const float* __restrict__ w1, const float* __restrict__ b1,
    const float* __restrict__ w2, const float* __restrict__ b2,
    const float* __restrict__ ln2g, const float* __restrict__ ln2b,
    float* __restrict__ h, int nchunk) {
  __shared__ float als[32][32];   // attno, then post-LN1 h
  __shared__ float wols[32][32];
  __shared__ float hs[32][32];    // residual h (pre-attn)
  __shared__ float ys[32][33];
  __shared__ float w1s[32][64];
  __shared__ float w2s[64][32];
  __shared__ float mids[32][64];
  const int t = threadIdx.x;
  const int r0 = blockIdx.x * 32;

  // stage: combine attn partials -> als (attno), weights, residual h
  {
    const int el = t * 4;
    const int row = r0 + (el >> 5);
    const int hh = (el >> 3) & 3;  // constant across the 4 elems (4-aligned)
    float4 s4 = make_float4(0.f, 0.f, 0.f, 0.f);
    float L = 0.f;
    for (int jc = 0; jc < nchunk; ++jc) {
      const float4 p4 = *(const float4*)&apacc[(size_t)jc * N * 32 + (size_t)r0 * 32 + el];
      s4.x += p4.x; s4.y += p4.y; s4.z += p4.z; s4.w += p4.w;
      L += apl[(size_t)jc * N * 4 + (size_t)row * 4 + hh];
    }
    float4 a4;
    a4.x = s4.x / L; a4.y = s4.y / L; a4.z = s4.z / L; a4.w = s4.w / L;
    ((float4*)&als[0][0])[t] = a4;
  }
  ((float4*)&wols[0][0])[t] = ((const float4*)wo)[t];
  ((float4*)&hs[0][0])[t] = ((const float4*)(h + (size_t)r0 * 32))[t];
#pragma unroll
  for (int i = 0; i < 2; ++i) {
    ((float4*)&w1s[0][0])[t + i * 256] = ((const float4*)w1)[t + i * 256];
    ((float4*)&w2s[0][0])[t + i * 256] = ((const float4*)w2)[t + i * 256];
  }
  __syncthreads();

  const int j = t & 31, og = t >> 5;
  // O-projection + residual
  {
    float acc[4];
#pragma unroll
    for (int u = 0; u < 4; ++u) acc[u] = bo[j];
    for (int kk = 0; kk < 32; ++kk) {
      const float w = wols[kk][j];
#pragma unroll
      for (int u = 0; u < 4; ++u) acc[u] = fmaf(als[og * 4 + u][kk], w, acc[u]);
    }
#pragma unroll
    for (int u = 0; u < 4; ++u) {
      const int r = og * 4 + u;
      ys[r][j] = hs[r][j] + acc[u];
    }
  }
  __syncthreads();
  // LayerNorm1 -> als (post-LN1 h, LDS only)
  if (t < 32) {
    float mu = 0.f;
#pragma unroll
    for (int c = 0; c < 32; ++c) mu += ys[t][c];
    mu *= (1.f / 32.f);
    float var = 0.f;
#pragma unroll
    for (int c = 0; c < 32; ++c) {
      const float dd = ys[t][c] - mu;
      var = fmaf(dd, dd, var);
    }
    var *= (1.f / 32.f);
    const float rs = rsqrtf(var + 1e-5f);
#pragma unroll
    for (int c = 0; c < 32; ++c)
      als[t][c] = (ys[t][c] - mu) * rs * ln1g[c] + ln1b[c];
  }
  __syncthreads();
  // FFN layer 1: 32 -> 64, relu
  {
    const int jm = t & 63, gg = t >> 6;
    float acc[8];
#pragma unroll
    for (int u = 0; u < 8; ++u) acc[u] = b1[jm];
    for (int kk = 0; kk < 32; ++kk) {
      const float w = w1s[kk][jm];
#pragma unroll
      for (int u = 0; u < 8; ++u) acc[u] = fmaf(als[gg * 8 + u][kk], w, acc[u]);
    }
#pragma unroll
    for (int u = 0; u < 8; ++u) mids[gg * 8 + u][jm] = fmaxf(acc[u], 0.f);
  }
  __syncthreads();
  // FFN layer 2: 64 -> 32 + residual (post-LN1 h in als)
  {
    float acc[4];
#pragma unroll
    for (int u = 0; u < 4; ++u) acc[u] = b2[j];
    for (int kk = 0; kk < 64; ++kk) {
      const float w = w2s[kk][j];
#pragma unroll
      for (int u = 0; u < 4; ++u) acc[u] = fmaf(mids[og * 4 + u][kk], w, acc[u]);
    }
#pragma unroll
    for (int u = 0; u < 4; ++u) {
      const int r = og * 4 + u;
      ys[r][j] = als[r][j] + acc[u];
    }
  }
  __syncthreads();
  // LayerNorm2 -> h global
  if (t < 32) {
    float mu = 0.f;
#pragma unroll
    for (int c = 0; c < 32; ++c) mu += ys[t][c];
    mu *= (1.f / 32.f);
    float var = 0.f;
#pragma unroll
    for (int c = 0; c < 32; ++c) {
      const float dd = ys[t][c] - mu;
      var = fmaf(dd, dd, var);
    }
    var *= (1.f / 32.f);
    const float rs = rsqrtf(var + 1e-5f);
#pragma unroll
    for (int c = 0; c < 32; ++c)
      h[(size_t)(r0 + t) * 32 + c] = (ys[t][c] - mu) * rs * ln2g[c] + ln2b[c];
  }
}

// ---------------- head ----------------
__global__ __launch_bounds__(256) void headp_kernel(const float* __restrict__ h,
                                                    float* __restrict__ partial) {
  __shared__ float red[8][32];
  const int t = threadIdx.x;
  const int c = t & 31, rg = t >> 5;
  const int r0 = blockIdx.x * 64;
  float s = 0.f;
#pragma unroll
  for (int u = 0; u < 8; ++u) s += h[(size_t)(r0 + rg * 8 + u) * 32 + c];
  red[rg][c] = s;
  __syncthreads();
  if (t < 32) {
    float ss = 0.f;
#pragma unroll
    for (int u = 0; u < 8; ++u) ss += red[u][t];
    partial[blockIdx.x * 32 + t] = ss;
  }
}

__global__ __launch_bounds__(64) void headf_kernel(const float* __restrict__ partial,
                                                   const float* __restrict__ w1,
                                                   const float* __restrict__ b1,
                                                   const float* __restrict__ w2,
                                                   const float* __restrict__ b2,
                                                   float* __restrict__ out) {
  __shared__ float mls[32];
  __shared__ float tls[16];
  const int t = threadIdx.x;
  if (t < 32) {
    float s = 0.f;
    for (int bb = 0; bb < 64; ++bb) s += partial[bb * 32 + t];
    mls[t] = s * (1.f / 4096.f);
  }
  __syncthreads();
  if (t < 16) {
    float a = b1[t];
#pragma unroll
    for (int c = 0; c < 32; ++c) a = fmaf(mls[c], w1[c * 16 + t], a);
    tls[t] = tanhf(a);
  }
  __syncthreads();
  if (t == 0) {
    float o = b2[0];
#pragma unroll
    for (int jj = 0; jj < 16; ++jj) o = fmaf(tls[jj], w2[jj], o);
    out[0] = o;
  }
}

extern "C" void kernel_launch(void* const* d_in, const int* in_sizes, int n_in,
                              void* d_out, int out_size, void* d_ws, size_t ws_size,
                              hipStream_t stream) {
  const float* x      = (const float*)d_in[0];
  const float* enc_w1 = (const float*)d_in[1];
  const float* enc_b1 = (const float*)d_in[2];
  const float* enc_w2 = (const float*)d_in[3];
  const float* enc_b2 = (const float*)d_in[4];
  const float* enc_w3 = (const float*)d_in[5];
  const float* enc_b3 = (const float*)d_in[6];
  const float* wq     = (const float*)d_in[7];
  const float* bq     = (const float*)d_in[8];
  const float* wk     = (const float*)d_in[9];
  const float* bk     = (const float*)d_in[10];
  const float* wv     = (const float*)d_in[11];
  const float* bv     = (const float*)d_in[12];
  const float* wo     = (const float*)d_in[13];
  const float* bo     = (const float*)d_in[14];
  const float* ln1_g  = (const float*)d_in[15];
  const float* ln1_b  = (const float*)d_in[16];
  const float* ffn_w1 = (const float*)d_in[17];
  const float* ffn_b1 = (const float*)d_in[18];
  const float* ffn_w2 = (const float*)d_in[19];
  const float* ffn_b2 = (const float*)d_in[20];
  const float* ln2_g  = (const float*)d_in[21];
  const float* ln2_b  = (const float*)d_in[22];
  const float* head_w1 = (const float*)d_in[23];
  const float* head_b1 = (const float*)d_in[24];
  const float* head_w2 = (const float*)d_in[25];
  const float* head_b2 = (const float*)d_in[26];

  float* ws      = (float*)d_ws;
  float* latent  = ws;                    // 131072
  float* normed  = ws + 131072;           // 131072
  float* h       = ws + 262144;           // 131072
  float* q       = ws + 393216;           // 131072
  float* k       = ws + 524288;           // 131072
  float* v       = ws + 655360;           // 131072
  const size_t base = 917504;             // shared region: pool partials, then attn partials

  // attn chunk count: 16 if the workspace can hold the doubled partials, else 8 (R12
  // behavior). Offsets are formula-driven and reduce to the old layout at NC=8.
  const size_t need16 = (base + (size_t)16 * 131072 + (size_t)16 * 16384 + 64 + 2048) *
                        sizeof(float);
  const int NC = (ws_size >= need16) ? 16 : 8;

  float* p_acc   = ws + base;                      // pool: 8*131072 (pool stays JC=8)
  float* p_deg   = p_acc + (size_t)8 * 131072;     // pool: 8*4096
  float* a_acc   = ws + base;                      // attn: NC*131072 (time-disjoint w/ pool)
  float* a_l     = a_acc + (size_t)NC * 131072;    // attn: NC*16384
  int*   kmax2i  = (int*)(a_l + (size_t)NC * 16384);  // 8 ints (4 per transformer block)
  float* partial = (float*)(kmax2i + 64);          // 2048

  hipMemsetAsync(kmax2i, 0, 8 * sizeof(int), stream);

  enc_kernel<<<512, 256, 0, stream>>>(x, enc_w1, enc_b1, enc_w2, enc_b2, enc_w3, enc_b3,
                                      latent, normed);
  pool_kernel<<<dim3(64, JC), 256, 0, stream>>>(normed, latent, p_acc, p_deg);

  for (int blk = 0; blk < 2; ++blk) {
    qkv_kernel<<<128, 256, 0, stream>>>(h, wq + blk * 1024, bq + blk * 32,
                                        wk + blk * 1024, bk + blk * 32,
                                        wv + blk * 1024, bv + blk * 32, q, k, v,
                                        kmax2i + blk * 4,
                                        latent, p_acc, p_deg, blk == 0 ? 1 : 0);
    attn_kernel<<<dim3(128, NC), 256, 0, stream>>>(q, k, v, kmax2i + blk * 4, a_acc, a_l,
                                                   N / NC);
    oln1ffn_kernel<<<128, 256, 0, stream>>>(a_acc, a_l,
                                            wo + blk * 1024, bo + blk * 32,
                                            ln1_g + blk * 32, ln1_b + blk * 32,
                                            ffn_w1 + blk * 2048, ffn_b1 + blk * 64,
                                            ffn_w2 + blk * 2048, ffn_b2 + blk * 32,
                                            ln2_g + blk * 32, ln2_b + blk * 32, h, NC);
  }

  headp_kernel<<<64, 256, 0, stream>>>(h, partial);
  headf_kernel<<<1, 64, 0, stream>>>(partial, head_w1, head_b1, head_w2, head_b2, (float*)d_out);
}

// Round 14
// 159.853 us; speedup vs baseline: 1.0814x; 1.0814x over previous
//
#include <hip/hip_runtime.h>
#include <math.h>

#define N 4096
#define DIN 512
#define D 32
#define JC 8

typedef float v2f __attribute__((ext_vector_type(2)));
__device__ __forceinline__ v2f fma2(v2f a, float b, v2f c) {
  v2f bb; bb.x = b; bb.y = b;
  return __builtin_elementwise_fma(a, bb, c);
}

// ---------------- encoder: x[4096,512] -> latent[4096,32] + normed rows, fused ----------------
// R6: k-split layer 1 (w1 read once per block; partials reduced via LDS). Left top-5.
__global__ __launch_bounds__(256) void enc_kernel(
    const float* __restrict__ x,
    const float* __restrict__ w1, const float* __restrict__ b1,
    const float* __restrict__ w2, const float* __restrict__ b2,
    const float* __restrict__ w3, const float* __restrict__ b3,
    float* __restrict__ latent, float* __restrict__ normed) {
  __shared__ float xs[8][512];       // 16 KB
  __shared__ float h1p[4][8][128];   // 16 KB layer-1 partials (per k-quarter)
  __shared__ float h1s[8][128];      // 4 KB
  __shared__ float h2s[8][64];       // 2 KB
  __shared__ float w2s[128][64];     // 32 KB
  __shared__ float w3s[64][32];      // 8 KB   -> total 78 KB = 2 blocks/CU
  const int t = threadIdx.x;
  const int r0 = blockIdx.x * 8;

  // stage x rows + w2 + w3 into LDS (one barrier covers all)
  const float4* xg = (const float4*)(x + (size_t)r0 * DIN);
  float4* xl = (float4*)&xs[0][0];
#pragma unroll
  for (int i = 0; i < 4; ++i) xl[t + i * 256] = xg[t + i * 256];
  float4* w2l = (float4*)&w2s[0][0];
  const float4* w2g = (const float4*)w2;
#pragma unroll
  for (int i = 0; i < 8; ++i) w2l[t + i * 256] = w2g[t + i * 256];
  float4* w3l = (float4*)&w3s[0][0];
  const float4* w3g = (const float4*)w3;
#pragma unroll
  for (int i = 0; i < 2; ++i) w3l[t + i * 256] = w3g[t + i * 256];
  __syncthreads();

  // layer 1: 512 -> 128. wave kq handles its k-quarter for all 8 rows x 2 cols.
  {
    const int jc2 = (t & 63) * 2;
    const int kq = t >> 6;
    const int kb = kq * 128;
    float a0[8], a1[8];
#pragma unroll
    for (int r = 0; r < 8; ++r) { a0[r] = 0.f; a1[r] = 0.f; }
    const float* wp = w1 + (size_t)kb * 128 + jc2;

#define ENC_LD4(P0, P1, P2, P3, KK)                          \
    P0 = *(const float2*)&wp[(size_t)(KK) * 128];            \
    P1 = *(const float2*)&wp[(size_t)((KK) + 1) * 128];      \
    P2 = *(const float2*)&wp[(size_t)((KK) + 2) * 128];      \
    P3 = *(const float2*)&wp[(size_t)((KK) + 3) * 128];

#define ENC_STEP(W0, WA, WB, WC, KK)                                   \
    {                                                                  \
      _Pragma("unroll")                                                \
      for (int r = 0; r < 8; ++r) {                                    \
        const float4 xv = *(const float4*)&xs[r][kb + (KK)];           \
        a0[r] = fmaf(xv.x, W0.x, a0[r]); a1[r] = fmaf(xv.x, W0.y, a1[r]); \
        a0[r] = fmaf(xv.y, WA.x, a0[r]); a1[r] = fmaf(xv.y, WA.y, a1[r]); \
        a0[r] = fmaf(xv.z, WB.x, a0[r]); a1[r] = fmaf(xv.z, WB.y, a1[r]); \
        a0[r] = fmaf(xv.w, WC.x, a0[r]); a1[r] = fmaf(xv.w, WC.y, a1[r]); \
      }                                                                \
    }

    float2 A0, A1, A2, A3, B0, B1, B2, B3, C0, C1, C2, C3, D0, D1, D2, D3;
    ENC_LD4(A0, A1, A2, A3, 0)
    ENC_LD4(B0, B1, B2, B3, 4)
    ENC_LD4(C0, C1, C2, C3, 8)
    ENC_LD4(D0, D1, D2, D3, 12)
    for (int kk = 0; kk < 128; kk += 16) {
      ENC_STEP(A0, A1, A2, A3, kk + 0);
      if (kk + 16 < 128) { ENC_LD4(A0, A1, A2, A3, kk + 16) }
      ENC_STEP(B0, B1, B2, B3, kk + 4);
      if (kk + 20 < 128) { ENC_LD4(B0, B1, B2, B3, kk + 20) }
      ENC_STEP(C0, C1, C2, C3, kk + 8);
      if (kk + 24 < 128) { ENC_LD4(C0, C1, C2, C3, kk + 24) }
      ENC_STEP(D0, D1, D2, D3, kk + 12);
      if (kk + 28 < 128) { ENC_LD4(D0, D1, D2, D3, kk + 28) }
    }
#undef ENC_STEP
#undef ENC_LD4
#pragma unroll
    for (int r = 0; r < 8; ++r) {
      h1p[kq][r][jc2] = a0[r];
      h1p[kq][r][jc2 + 1] = a1[r];
    }
  }
  __syncthreads();

  // reduce the 4 k-quarter partials + bias + relu (1024 outputs)
#pragma unroll
  for (int e0 = 0; e0 < 1024; e0 += 256) {
    const int e = e0 + t;
    const int r = e >> 7, c = e & 127;
    const float s = b1[c] + ((h1p[0][r][c] + h1p[1][r][c]) + (h1p[2][r][c] + h1p[3][r][c]));
    h1s[r][c] = fmaxf(s, 0.f);
  }
  __syncthreads();

  // layer 2: 128 -> 64, relu. weights from LDS (w2s), h1 broadcast reads
  {
    const int j = t & 63, rg = t >> 6;
    const int ra = rg * 2, rb = ra + 1;
    float a0 = b2[j], a1 = b2[j];
#pragma unroll 8
    for (int kk = 0; kk < 128; ++kk) {
      const float w = w2s[kk][j];
      a0 = fmaf(h1s[ra][kk], w, a0);
      a1 = fmaf(h1s[rb][kk], w, a1);
    }
    h2s[ra][j] = fmaxf(a0, 0.f);
    h2s[rb][j] = fmaxf(a1, 0.f);
  }
  __syncthreads();

  // layer 3: 64 -> 32 + fused row-normalize (shfl reduce over the 32 j-lanes)
  {
    const int j = t & 31, og = t >> 5;  // 8 rows, 1 per group
    float acc = b3[j];
#pragma unroll 8
    for (int kk = 0; kk < 64; ++kk) acc = fmaf(h2s[og][kk], w3s[kk][j], acc);
    float s2 = acc * acc;
    s2 += __shfl_xor(s2, 1);
    s2 += __shfl_xor(s2, 2);
    s2 += __shfl_xor(s2, 4);
    s2 += __shfl_xor(s2, 8);
    s2 += __shfl_xor(s2, 16);
    const float inv = 1.0f / (sqrtf(s2) + 1e-12f);
    const size_t off = (size_t)(r0 + og) * D + j;
    latent[off] = acc;
    normed[off] = acc * inv;
  }
}

// ---------------- graph pool partials: block (bi, bj) covers 64 i-rows x 512 j ----------------
// R11: 2 i-rows/thread + packed fma + XOR swizzle (conflict-free) + butterfly reduce.
__global__ __launch_bounds__(256) __attribute__((amdgpu_waves_per_eu(2, 2)))
void pool_kernel(const float* __restrict__ normed,
                 const float* __restrict__ latent,
                 float* __restrict__ pacc,
                 float* __restrict__ pdeg) {
  __shared__ float smem[8192];
  float* nt = smem;
  float* lt = smem + 4096;
  const int t = threadIdx.x;
  const int jg = t & 7, ip = t >> 3;  // ip in [0,32)
  const int i0 = blockIdx.x * 64;
  const int j0 = blockIdx.y * 512;

  v2f nip[32];
  {
    const float* nr0 = normed + (size_t)(i0 + ip) * D;
    const float* nr1 = normed + (size_t)(i0 + ip + 32) * D;
#pragma unroll
    for (int c = 0; c < 32; ++c) { nip[c].x = nr0[c]; nip[c].y = nr1[c]; }
  }

  v2f accp[32], deg2;
#pragma unroll
  for (int c = 0; c < 32; ++c) { accp[c].x = 0.f; accp[c].y = 0.f; }
  deg2.x = 0.f; deg2.y = 0.f;

  for (int jt = j0; jt < j0 + 512; jt += 128) {
    __syncthreads();
    const float4* ng = (const float4*)(normed + (size_t)jt * D);
    const float4* lg = (const float4*)(latent + (size_t)jt * D);
    float4* ntl = (float4*)nt;
    float4* ltl = (float4*)lt;
#pragma unroll
    for (int i = 0; i < 4; ++i) {
      const int gidx = t + i * 256;  // [0,1024): row r = gidx>>3, slot cc = gidx&7
      const int r = gidx >> 3, cc = gidx & 7, slot = cc ^ (r & 7);
      ntl[r * 8 + slot] = ng[gidx];
      ltl[r * 8 + slot] = lg[gidx];
    }
    __syncthreads();
#pragma unroll 2
    for (int jj = jg; jj < 128; jj += 8) {
      const float4* nr = (const float4*)nt + jj * 8;
      const int sw = jj & 7;
      v2f s2; s2.x = 0.f; s2.y = 0.f;
#pragma unroll
      for (int c4 = 0; c4 < 8; ++c4) {
        const float4 nv = nr[c4 ^ sw];
        s2 = fma2(nip[c4 * 4 + 0], nv.x, s2);
        s2 = fma2(nip[c4 * 4 + 1], nv.y, s2);
        s2 = fma2(nip[c4 * 4 + 2], nv.z, s2);
        s2 = fma2(nip[c4 * 4 + 3], nv.w, s2);
      }
      if (s2.x >= 0.9f || s2.y >= 0.9f) {
        v2f m2;
        m2.x = (s2.x >= 0.9f) ? 1.f : 0.f;
        m2.y = (s2.y >= 0.9f) ? 1.f : 0.f;
        deg2 += m2;
        const float4* lr = (const float4*)lt + jj * 8;
#pragma unroll
        for (int c4 = 0; c4 < 8; ++c4) {
          const float4 lv = lr[c4 ^ sw];
          accp[c4 * 4 + 0] = fma2(m2, lv.x, accp[c4 * 4 + 0]);
          accp[c4 * 4 + 1] = fma2(m2, lv.y, accp[c4 * 4 + 1]);
          accp[c4 * 4 + 2] = fma2(m2, lv.z, accp[c4 * 4 + 2]);
          accp[c4 * 4 + 3] = fma2(m2, lv.w, accp[c4 * 4 + 3]);
        }
      }
    }
  }
  // butterfly-reduce the 8 jg partials (jg = lane bits 0..2)
#pragma unroll
  for (int m = 1; m <= 4; m <<= 1) {
#pragma unroll
    for (int c = 0; c < 32; ++c) {
      accp[c].x += __shfl_xor(accp[c].x, m);
      accp[c].y += __shfl_xor(accp[c].y, m);
    }
    deg2.x += __shfl_xor(deg2.x, m);
    deg2.y += __shfl_xor(deg2.y, m);
  }
  if (jg == 0) {
    float* pa0 = pacc + ((size_t)blockIdx.y * N + i0 + ip) * 32;
    float* pa1 = pacc + ((size_t)blockIdx.y * N + i0 + ip + 32) * 32;
#pragma unroll
    for (int c = 0; c < 32; ++c) {
      pa0[c] = accp[c].x;
      pa1[c] = accp[c].y;
    }
    pdeg[(size_t)blockIdx.y * N + i0 + ip] = deg2.x;
    pdeg[(size_t)blockIdx.y * N + i0 + ip + 32] = deg2.y;
  }
}

// ---------------- fused QKV projection (+ optional pool-combine producing h) ----------------
// R12: pool_combine folded in (blk 0). Bit-identical combine (jc ascending, one division).
__global__ __launch_bounds__(256) void qkv_kernel(
    float* __restrict__ h,
    const float* __restrict__ wq, const float* __restrict__ bq,
    const float* __restrict__ wk, const float* __restrict__ bk,
    const float* __restrict__ wv, const float* __restrict__ bv,
    float* __restrict__ q, float* __restrict__ k, float* __restrict__ v,
    int* __restrict__ kmax2i,
    const float* __restrict__ latent,
    const float* __restrict__ pacc,
    const float* __restrict__ pdeg,
    int fuse_combine) {
  __shared__ float hs[32][32];
  __shared__ float wsm[3][32][32];
  __shared__ int kred[4];
  const int t = threadIdx.x;
  const int r0 = blockIdx.x * 32;
  if (t < 4) kred[t] = 0;
  if (fuse_combine) {
    const int el = t * 4;                 // element offset within the 32x32 tile
    const int gi = r0 + (el >> 5);        // global row (all 4 elems same row)
    float4 s4 = make_float4(0.f, 0.f, 0.f, 0.f);
    float dg = 0.f;
#pragma unroll
    for (int jc = 0; jc < JC; ++jc) {
      const float4 p4 = *(const float4*)&pacc[(size_t)jc * N * 32 + (size_t)r0 * 32 + el];
      s4.x += p4.x; s4.y += p4.y; s4.z += p4.z; s4.w += p4.w;
      dg += pdeg[(size_t)jc * N + gi];
    }
    const float4 l4 = *(const float4*)&latent[(size_t)r0 * 32 + el];
    float4 h4;
    h4.x = l4.x + s4.x / dg;
    h4.y = l4.y + s4.y / dg;
    h4.z = l4.z + s4.z / dg;
    h4.w = l4.w + s4.w / dg;
    ((float4*)&hs[0][0])[t] = h4;
    *(float4*)&h[(size_t)r0 * 32 + el] = h4;
  } else {
    ((float4*)&hs[0][0])[t] = ((const float4*)(h + (size_t)r0 * 32))[t];
  }
  ((float4*)&wsm[0][0][0])[t] = ((const float4*)wq)[t];
  ((float4*)&wsm[1][0][0])[t] = ((const float4*)wk)[t];
  ((float4*)&wsm[2][0][0])[t] = ((const float4*)wv)[t];
  __syncthreads();
  const int j = t & 31, og = t >> 5;
  const int head = j >> 3;
  float aq[4], ak[4], av[4];
#pragma unroll
  for (int u = 0; u < 4; ++u) { aq[u] = bq[j]; ak[u] = bk[j]; av[u] = bv[j]; }
  for (int kk = 0; kk < 32; ++kk) {
    const float wqv = wsm[0][kk][j], wkv = wsm[1][kk][j], wvv = wsm[2][kk][j];
#pragma unroll
    for (int u = 0; u < 4; ++u) {
      const float hh = hs[og * 4 + u][kk];
      aq[u] = fmaf(hh, wqv, aq[u]);
      ak[u] = fmaf(hh, wkv, ak[u]);
      av[u] = fmaf(hh, wvv, av[u]);
    }
  }
  const float scale = 1.4426950408889634f * 0.35355339059327373f;  // log2(e)/sqrt(8)
#pragma unroll
  for (int u = 0; u < 4; ++u) {
    const size_t off = (size_t)(r0 + og * 4 + u) * 32 + j;
    q[off] = aq[u] * scale;
    k[off] = ak[u];
    v[off] = av[u];
  }
  // per-(row,head) ||k8||^2 via shfl over the 8 lanes of this head; block-max; global atomicMax
#pragma unroll
  for (int u = 0; u < 4; ++u) {
    float s2 = ak[u] * ak[u];
    s2 += __shfl_xor(s2, 1);
    s2 += __shfl_xor(s2, 2);
    s2 += __shfl_xor(s2, 4);
    if ((j & 7) == 0) atomicMax(&kred[head], __float_as_int(s2));
  }
  __syncthreads();
  if (t < 4) atomicMax(&kmax2i[t], kred[t]);
}

// ---------------- attention partials: block (rowBlk, jChunk); 32 rows x 512 j ----------------
// R9/R12 final: 32 rows/block, pr=2 packed pairs, grid 128x8 = 4 blocks/CU. R13's NC=16
// regressed: 64 VGPR caps residency at 16 waves/CU (m69 buckets) = 4 blocks, so more
// chunks only added partial-traffic + sequential rounds. This decomposition's floor.
__global__ __launch_bounds__(256, 4)
void attn_kernel(const float* __restrict__ q,
                 const float* __restrict__ k,
                 const float* __restrict__ v,
                 const int* __restrict__ kmax2i,
                 float* __restrict__ apacc,
                 float* __restrict__ apl) {
  __shared__ float4 tiles[1024];  // kls[64*8] | vls[64*8], chunk-XOR swizzled
  float4* kls = tiles;
  float4* vls = tiles + 512;
  const int t = threadIdx.x;
  const int jg = t & 7, head = (t >> 3) & 3, rg = t >> 5;
  const int r0 = blockIdx.x * 32;
  const int j0 = blockIdx.y * (N / JC);

  const float km2 = __int_as_float(kmax2i[head]);

  // q-row pairs: component c of rows (2pr, 2pr+1) in lo/hi of qq[pr][c]
  v2f qq[2][8], acc[2][8], mneg2[2], l2[2];
#pragma unroll
  for (int pr = 0; pr < 2; ++pr) {
    const float* qr0 = q + (size_t)(r0 + rg * 4 + 2 * pr) * 32 + head * 8;
    const float* qr1 = qr0 + 32;
    const float4 qa0 = ((const float4*)qr0)[0], qb0 = ((const float4*)qr0)[1];
    const float4 qa1 = ((const float4*)qr1)[0], qb1 = ((const float4*)qr1)[1];
    qq[pr][0].x = qa0.x; qq[pr][0].y = qa1.x;
    qq[pr][1].x = qa0.y; qq[pr][1].y = qa1.y;
    qq[pr][2].x = qa0.z; qq[pr][2].y = qa1.z;
    qq[pr][3].x = qa0.w; qq[pr][3].y = qa1.w;
    qq[pr][4].x = qb0.x; qq[pr][4].y = qb1.x;
    qq[pr][5].x = qb0.y; qq[pr][5].y = qb1.y;
    qq[pr][6].x = qb0.z; qq[pr][6].y = qb1.z;
    qq[pr][7].x = qb0.w; qq[pr][7].y = qb1.w;
    const float qn0 = qa0.x * qa0.x + qa0.y * qa0.y + qa0.z * qa0.z + qa0.w * qa0.w +
                      qb0.x * qb0.x + qb0.y * qb0.y + qb0.z * qb0.z + qb0.w * qb0.w;
    const float qn1 = qa1.x * qa1.x + qa1.y * qa1.y + qa1.z * qa1.z + qa1.w * qa1.w +
                      qb1.x * qb1.x + qb1.y * qb1.y + qb1.z * qb1.z + qb1.w * qb1.w;
    mneg2[pr].x = -sqrtf(qn0 * km2);
    mneg2[pr].y = -sqrtf(qn1 * km2);
    l2[pr].x = 0.f; l2[pr].y = 0.f;
#pragma unroll
    for (int c = 0; c < 8; ++c) { acc[pr][c].x = 0.f; acc[pr][c].y = 0.f; }
  }

  // prologue: load tile 0 into registers
  float4 kr0, kr1, vr0, vr1;
  {
    const float4* kg = (const float4*)(k + (size_t)j0 * 32);
    const float4* vg = (const float4*)(v + (size_t)j0 * 32);
    kr0 = kg[t]; kr1 = kg[t + 256];
    vr0 = vg[t]; vr1 = vg[t + 256];
  }

  // precomputed swizzle slots for the two staged quarters
  const int rA = t >> 3, slotA = (t & 7) ^ (rA & 7);
  const int g1 = t + 256;
  const int rB = g1 >> 3, slotB = (g1 & 7) ^ (rB & 7);

  const int h2 = head * 2;
  const int s0 = h2 ^ jg, s1 = (h2 + 1) ^ jg;
  for (int jt = j0; jt < j0 + (N / JC); jt += 64) {
    __syncthreads();
    kls[rA * 8 + slotA] = kr0;
    kls[rB * 8 + slotB] = kr1;
    vls[rA * 8 + slotA] = vr0;
    vls[rB * 8 + slotB] = vr1;
    __syncthreads();
    if (jt + 64 < j0 + (N / JC)) {
      const float4* kg = (const float4*)(k + (size_t)(jt + 64) * 32);
      const float4* vg = (const float4*)(v + (size_t)(jt + 64) * 32);
      kr0 = kg[t]; kr1 = kg[t + 256];
      vr0 = vg[t]; vr1 = vg[t + 256];
    }
#pragma unroll 2
    for (int it = 0; it < 8; ++it) {
      const int jj = it * 8 + jg;
      const float4 ka = kls[jj * 8 + s0];
      const float4 kb = kls[jj * 8 + s1];
      const float4 va = vls[jj * 8 + s0];
      const float4 vb = vls[jj * 8 + s1];
#pragma unroll
      for (int pr = 0; pr < 2; ++pr) {
        v2f s2 = mneg2[pr];
        s2 = fma2(qq[pr][0], ka.x, s2);
        s2 = fma2(qq[pr][1], ka.y, s2);
        s2 = fma2(qq[pr][2], ka.z, s2);
        s2 = fma2(qq[pr][3], ka.w, s2);
        s2 = fma2(qq[pr][4], kb.x, s2);
        s2 = fma2(qq[pr][5], kb.y, s2);
        s2 = fma2(qq[pr][6], kb.z, s2);
        s2 = fma2(qq[pr][7], kb.w, s2);
        v2f p2;
        p2.x = __builtin_amdgcn_exp2f(s2.x);
        p2.y = __builtin_amdgcn_exp2f(s2.y);
        l2[pr] += p2;
        acc[pr][0] = fma2(p2, va.x, acc[pr][0]);
        acc[pr][1] = fma2(p2, va.y, acc[pr][1]);
        acc[pr][2] = fma2(p2, va.z, acc[pr][2]);
        acc[pr][3] = fma2(p2, va.w, acc[pr][3]);
        acc[pr][4] = fma2(p2, vb.x, acc[pr][4]);
        acc[pr][5] = fma2(p2, vb.y, acc[pr][5]);
        acc[pr][6] = fma2(p2, vb.z, acc[pr][6]);
        acc[pr][7] = fma2(p2, vb.w, acc[pr][7]);
      }
    }
  }
  // butterfly-reduce the 8 jg partials (jg = lane bits 0..2); all lanes end with the sum
#pragma unroll
  for (int pr = 0; pr < 2; ++pr) {
#pragma unroll
    for (int m = 1; m <= 4; m <<= 1) {
#pragma unroll
      for (int c = 0; c < 8; ++c) {
        acc[pr][c].x += __shfl_xor(acc[pr][c].x, m);
        acc[pr][c].y += __shfl_xor(acc[pr][c].y, m);
      }
      l2[pr].x += __shfl_xor(l2[pr].x, m);
      l2[pr].y += __shfl_xor(l2[pr].y, m);
    }
  }
  if (jg == 0) {
    const size_t abase = (size_t)blockIdx.y * N * 32;
    const size_t lbase = (size_t)blockIdx.y * N * 4;
#pragma unroll
    for (int pr = 0; pr < 2; ++pr) {
      const int row0 = r0 + rg * 4 + 2 * pr;
      float* ap0 = apacc + abase + (size_t)row0 * 32 + head * 8;
      float* ap1 = ap0 + 32;
#pragma unroll
      for (int c = 0; c < 8; ++c) {
        ap0[c] = acc[pr][c].x;
        ap1[c] = acc[pr][c].y;
      }
      apl[lbase + (size_t)row0 * 4 + head] = l2[pr].x;
      apl[lbase + (size_t)(row0 + 1) * 4 + head] = l2[pr].y;
    }
  }
}

// ---------------- fused: attn-combine + O-proj + residual + LN1 + FFN + residual + LN2 ----
// R12: acombine + oln1 + ffn merged (all were 32-row-blocked). Staging computes attno
// in LDS directly from apacc/apl (jc ascending, one division -- bit-identical to the old
// acombine; attno never hits global). LN1 output stays in LDS (als reused) and feeds the
// FFN (intermediate h global write eliminated). Per-element arithmetic chains verbatim
// from the three originals. Saves 2 launches + 2 global round-trips per transformer blk.
__global__ __launch_bounds__(256) void oln1ffn_kernel(
    const float* __restrict__ apacc, const float* __restrict__ apl,
    const float* __restrict__ wo, const float* __restrict__ bo,
    const float* __restrict__ ln1g, const float* __restrict__ ln1b,
    const float* __restrict__ w1, const float* __restrict__ b1,
    const float* __restrict__ w2, const float* __restrict__ b2,
    const float* __restrict__ ln2g, const float* __restrict__ ln2b,
    float* __restrict__ h) {
  __shared__ float als[32][32];   // attno, then post-LN1 h
  __shared__ float wols[32][32];
  __shared__ float hs[32][32];    // residual h (pre-attn)
  __shared__ float ys[32][33];
  __shared__ float w1s[32][64];
  __shared__ float w2s[64][32];
  __shared__ float mids[32][64];
  const int t = threadIdx.x;
  const int r0 = blockIdx.x * 32;

  // stage: combine attn partials -> als (attno), weights, residual h
  {
    const int el = t * 4;
    const int row = r0 + (el >> 5);
    const int hh = (el >> 3) & 3;  // constant across the 4 elems (4-aligned)
    float4 s4 = make_float4(0.f, 0.f, 0.f, 0.f);
    float L = 0.f;
#pragma unroll
    for (int jc = 0; jc < JC; ++jc) {
      const float4 p4 = *(const float4*)&apacc[(size_t)jc * N * 32 + (size_t)r0 * 32 + el];
      s4.x += p4.x; s4.y += p4.y; s4.z += p4.z; s4.w += p4.w;
      L += apl[(size_t)jc * N * 4 + (size_t)row * 4 + hh];
    }
    float4 a4;
    a4.x = s4.x / L; a4.y = s4.y / L; a4.z = s4.z / L; a4.w = s4.w / L;
    ((float4*)&als[0][0])[t] = a4;
  }
  ((float4*)&wols[0][0])[t] = ((const float4*)wo)[t];
  ((float4*)&hs[0][0])[t] = ((const float4*)(h + (size_t)r0 * 32))[t];
#pragma unroll
  for (int i = 0; i < 2; ++i) {
    ((float4*)&w1s[0][0])[t + i * 256] = ((const float4*)w1)[t + i * 256];
    ((float4*)&w2s[0][0])[t + i * 256] = ((const float4*)w2)[t + i * 256];
  }
  __syncthreads();

  const int j = t & 31, og = t >> 5;
  // O-projection + residual
  {
    float acc[4];
#pragma unroll
    for (int u = 0; u < 4; ++u) acc[u] = bo[j];
    for (int kk = 0; kk < 32; ++kk) {
      const float w = wols[kk][j];
#pragma unroll
      for (int u = 0; u < 4; ++u) acc[u] = fmaf(als[og * 4 + u][kk], w, acc[u]);
    }
#pragma unroll
    for (int u = 0; u < 4; ++u) {
      const int r = og * 4 + u;
      ys[r][j] = hs[r][j] + acc[u];
    }
  }
  __syncthreads();
  // LayerNorm1 -> als (post-LN1 h, LDS only)
  if (t < 32) {
    float mu = 0.f;
#pragma unroll
    for (int c = 0; c < 32; ++c) mu += ys[t][c];
    mu *= (1.f / 32.f);
    float var = 0.f;
#pragma unroll
    for (int c = 0; c < 32; ++c) {
      const float dd = ys[t][c] - mu;
      var = fmaf(dd, dd, var);
    }
    var *= (1.f / 32.f);
    const float rs = rsqrtf(var + 1e-5f);
#pragma unroll
    for (int c = 0; c < 32; ++c)
      als[t][c] = (ys[t][c] - mu) * rs * ln1g[c] + ln1b[c];
  }
  __syncthreads();
  // FFN layer 1: 32 -> 64, relu
  {
    const int jm = t & 63, gg = t >> 6;
    float acc[8];
#pragma unroll
    for (int u = 0; u < 8; ++u) acc[u] = b1[jm];
    for (int kk = 0; kk < 32; ++kk) {
      const float w = w1s[kk][jm];
#pragma unroll
      for (int u = 0; u < 8; ++u) acc[u] = fmaf(als[gg * 8 + u][kk], w, acc[u]);
    }
#pragma unroll
    for (int u = 0; u < 8; ++u) mids[gg * 8 + u][jm] = fmaxf(acc[u], 0.f);
  }
  __syncthreads();
  // FFN layer 2: 64 -> 32 + residual (post-LN1 h in als)
  {
    float acc[4];
#pragma unroll
    for (int u = 0; u < 4; ++u) acc[u] = b2[j];
    for (int kk = 0; kk < 64; ++kk) {
      const float w = w2s[kk][j];
#pragma unroll
      for (int u = 0; u < 4; ++u) acc[u] = fmaf(mids[og * 4 + u][kk], w, acc[u]);
    }
#pragma unroll
    for (int u = 0; u < 4; ++u) {
      const int r = og * 4 + u;
      ys[r][j] = als[r][j] + acc[u];
    }
  }
  __syncthreads();
  // LayerNorm2 -> h global
  if (t < 32) {
    float mu = 0.f;
#pragma unroll
    for (int c = 0; c < 32; ++c) mu += ys[t][c];
    mu *= (1.f / 32.f);
    float var = 0.f;
#pragma unroll
    for (int c = 0; c < 32; ++c) {
      const float dd = ys[t][c] - mu;
      var = fmaf(dd, dd, var);
    }
    var *= (1.f / 32.f);
    const float rs = rsqrtf(var + 1e-5f);
#pragma unroll
    for (int c = 0; c < 32; ++c)
      h[(size_t)(r0 + t) * 32 + c] = (ys[t][c] - mu) * rs * ln2g[c] + ln2b[c];
  }
}

// ---------------- head ----------------
__global__ __launch_bounds__(256) void headp_kernel(const float* __restrict__ h,
                                                    float* __restrict__ partial) {
  __shared__ float red[8][32];
  const int t = threadIdx.x;
  const int c = t & 31, rg = t >> 5;
  const int r0 = blockIdx.x * 64;
  float s = 0.f;
#pragma unroll
  for (int u = 0; u < 8; ++u) s += h[(size_t)(r0 + rg * 8 + u) * 32 + c];
  red[rg][c] = s;
  __syncthreads();
  if (t < 32) {
    float ss = 0.f;
#pragma unroll
    for (int u = 0; u < 8; ++u) ss += red[u][t];
    partial[blockIdx.x * 32 + t] = ss;
  }
}

__global__ __launch_bounds__(64) void headf_kernel(const float* __restrict__ partial,
                                                   const float* __restrict__ w1,
                                                   const float* __restrict__ b1,
                                                   const float* __restrict__ w2,
                                                   const float* __restrict__ b2,
                                                   float* __restrict__ out) {
  __shared__ float mls[32];
  __shared__ float tls[16];
  const int t = threadIdx.x;
  if (t < 32) {
    float s = 0.f;
    for (int bb = 0; bb < 64; ++bb) s += partial[bb * 32 + t];
    mls[t] = s * (1.f / 4096.f);
  }
  __syncthreads();
  if (t < 16) {
    float a = b1[t];
#pragma unroll
    for (int c = 0; c < 32; ++c) a = fmaf(mls[c], w1[c * 16 + t], a);
    tls[t] = tanhf(a);
  }
  __syncthreads();
  if (t == 0) {
    float o = b2[0];
#pragma unroll
    for (int jj = 0; jj < 16; ++jj) o = fmaf(tls[jj], w2[jj], o);
    out[0] = o;
  }
}

extern "C" void kernel_launch(void* const* d_in, const int* in_sizes, int n_in,
                              void* d_out, int out_size, void* d_ws, size_t ws_size,
                              hipStream_t stream) {
  const float* x      = (const float*)d_in[0];
  const float* enc_w1 = (const float*)d_in[1];
  const float* enc_b1 = (const float*)d_in[2];
  const float* enc_w2 = (const float*)d_in[3];
  const float* enc_b2 = (const float*)d_in[4];
  const float* enc_w3 = (const float*)d_in[5];
  const float* enc_b3 = (const float*)d_in[6];
  const float* wq     = (const float*)d_in[7];
  const float* bq     = (const float*)d_in[8];
  const float* wk     = (const float*)d_in[9];
  const float* bk     = (const float*)d_in[10];
  const float* wv     = (const float*)d_in[11];
  const float* bv     = (const float*)d_in[12];
  const float* wo     = (const float*)d_in[13];
  const float* bo     = (const float*)d_in[14];
  const float* ln1_g  = (const float*)d_in[15];
  const float* ln1_b  = (const float*)d_in[16];
  const float* ffn_w1 = (const float*)d_in[17];
  const float* ffn_b1 = (const float*)d_in[18];
  const float* ffn_w2 = (const float*)d_in[19];
  const float* ffn_b2 = (const float*)d_in[20];
  const float* ln2_g  = (const float*)d_in[21];
  const float* ln2_b  = (const float*)d_in[22];
  const float* head_w1 = (const float*)d_in[23];
  const float* head_b1 = (const float*)d_in[24];
  const float* head_w2 = (const float*)d_in[25];
  const float* head_b2 = (const float*)d_in[26];

  float* ws      = (float*)d_ws;
  float* latent  = ws;                    // 131072
  float* normed  = ws + 131072;           // 131072
  float* h       = ws + 262144;           // 131072
  float* q       = ws + 393216;           // 131072
  float* k       = ws + 524288;           // 131072
  float* v       = ws + 655360;           // 131072
  float* shreg   = ws + 917504;           // shared region: pool partials, then attn partials
  float* p_acc   = shreg;                 // pool: 8*131072
  float* p_deg   = shreg + 1048576;       // pool: 8*4096
  float* a_acc   = shreg;                 // attn: 8*131072
  float* a_l     = shreg + 1048576;       // attn: 8*16384
  int*   kmax2i  = (int*)(ws + 2097152);  // 8 ints (4 per transformer block)
  float* partial = ws + 2097216;          // 2048

  hipMemsetAsync(kmax2i, 0, 8 * sizeof(int), stream);

  enc_kernel<<<512, 256, 0, stream>>>(x, enc_w1, enc_b1, enc_w2, enc_b2, enc_w3, enc_b3,
                                      latent, normed);
  pool_kernel<<<dim3(64, JC), 256, 0, stream>>>(normed, latent, p_acc, p_deg);

  for (int blk = 0; blk < 2; ++blk) {
    qkv_kernel<<<128, 256, 0, stream>>>(h, wq + blk * 1024, bq + blk * 32,
                                        wk + blk * 1024, bk + blk * 32,
                                        wv + blk * 1024, bv + blk * 32, q, k, v,
                                        kmax2i + blk * 4,
                                        latent, p_acc, p_deg, blk == 0 ? 1 : 0);
    attn_kernel<<<dim3(128, JC), 256, 0, stream>>>(q, k, v, kmax2i + blk * 4, a_acc, a_l);
    oln1ffn_kernel<<<128, 256, 0, stream>>>(a_acc, a_l,
                                            wo + blk * 1024, bo + blk * 32,
                                            ln1_g + blk * 32, ln1_b + blk * 32,
                                            ffn_w1 + blk * 2048, ffn_b1 + blk * 64,
                                            ffn_w2 + blk * 2048, ffn_b2 + blk * 32,
                                            ln2_g + blk * 32, ln2_b + blk * 32, h);
  }

  headp_kernel<<<64, 256, 0, stream>>>(h, partial);
  headf_kernel<<<1, 64, 0, stream>>>(partial, head_w1, head_b1, head_w2, head_b2, (float*)d_out);
}